// Round 4
// baseline (802.118 us; speedup 1.0000x reference)
//
#include <hip/hip_runtime.h>

#define N_NODES 100000
#define N_EDGES 20000
#define N_INC   800000
#define TDIM    384
#define HID     128
#define NOFF    800000   // node-ptr offset in merged scan
#define EPAD    8        // edge cursor stride (ints) = 32B
#define NPAD    4        // node cursor stride (ints) = 16B

#define PROJ_BLOCKS 1563
#define CNT_BLOCKS  512
#define FILLE_BLOCKS 1024
#define FILLN_BLOCKS 1024
#define CS_BLOCKS   256

typedef __attribute__((ext_vector_type(8))) short short8;
typedef __attribute__((ext_vector_type(4))) float floatx4;

static __device__ __forceinline__ unsigned short f32_bf16_rne(float f) {
  unsigned int u = __float_as_uint(f);
  unsigned int r = u + 0x7FFFu + ((u >> 16) & 1u);
  return (unsigned short)(r >> 16);
}

// ---------------- W prep: split W into hi/lo bf16 in B-fragment order ---------
__global__ __launch_bounds__(64) void wprep_kernel(
    const float* __restrict__ W, unsigned short* __restrict__ Bh,
    unsigned short* __restrict__ Bl)
{
  int b = blockIdx.x;              // 0..95 = kk*8 + nt
  int lane = threadIdx.x;
  int kk = b >> 3, nt = b & 7;
  int col = lane & 15, quad = lane >> 4;
  size_t o = ((size_t)b * 64 + lane) * 8;
#pragma unroll
  for (int j = 0; j < 8; ++j) {
    int k = kk * 32 + quad * 8 + j;
    float w = W[(size_t)k * HID + nt * 16 + col];
    unsigned short h = f32_bf16_rne(w);
    float hf = __uint_as_float((unsigned int)h << 16);
    Bh[o + j] = h;
    Bl[o + j] = f32_bf16_rne(w - hf);
  }
}

// ------------- fused: projection (MFMA bf16x3) + incidence counting ----------
// blocks [0,PROJ_BLOCKS): proj tile; blocks [PROJ_BLOCKS, +CNT_BLOCKS): count
__global__ __launch_bounds__(256) void proj_count_kernel(
    const float* __restrict__ A, const unsigned short* __restrict__ Bh,
    const unsigned short* __restrict__ Bl, const float* __restrict__ bias,
    float* __restrict__ H,
    const int* __restrict__ node_idx, const int* __restrict__ edge_idx,
    int* __restrict__ ecp, int* __restrict__ ncp)
{
  __shared__ unsigned short BhS[512 * 8];   // 8 KB
  __shared__ unsigned short BlS[512 * 8];   // 8 KB
  const int tid = threadIdx.x;

  if (blockIdx.x >= PROJ_BLOCKS) {
    // ---- count role: fire-and-forget atomics on padded counters ----
    int start = (blockIdx.x - PROJ_BLOCKS) * 256 + tid;
    for (int i = start; i < N_INC; i += CNT_BLOCKS * 256) {
      int ed = edge_idx[i];
      int nd = node_idx[i];
      atomicAdd(&ecp[ed * EPAD], 1);
      atomicAdd(&ncp[nd * NPAD], 1);
    }
    return;
  }

  // ---- proj role ----
  const int wave = tid >> 6;
  const int lane = tid & 63;
  const int col = lane & 15;
  const int quad = lane >> 4;
  const int m0 = blockIdx.x * 64 + wave * 16;

  floatx4 acc[8];
#pragma unroll
  for (int nt = 0; nt < 8; ++nt) acc[nt] = (floatx4){0.f, 0.f, 0.f, 0.f};

  int r = m0 + col;
  if (r >= N_NODES) r = N_NODES - 1;        // clamp loads; stores guarded
  const float* arow = A + (size_t)r * TDIM + quad * 8;

  float ra[8];
  *(float4*)(&ra[0]) = *(const float4*)(arow);
  *(float4*)(&ra[4]) = *(const float4*)(arow + 4);

  for (int kk = 0; kk < 12; ++kk) {
    short8 sh0 = *(const short8*)(Bh + ((size_t)kk * 512 + tid) * 8);
    short8 sh1 = *(const short8*)(Bh + ((size_t)kk * 512 + tid + 256) * 8);
    short8 sl0 = *(const short8*)(Bl + ((size_t)kk * 512 + tid) * 8);
    short8 sl1 = *(const short8*)(Bl + ((size_t)kk * 512 + tid + 256) * 8);
    __syncthreads();
    *(short8*)(BhS + (size_t)tid * 8) = sh0;
    *(short8*)(BhS + ((size_t)tid + 256) * 8) = sh1;
    *(short8*)(BlS + (size_t)tid * 8) = sl0;
    *(short8*)(BlS + ((size_t)tid + 256) * 8) = sl1;

    float rn[8];
    if (kk < 11) {
      *(float4*)(&rn[0]) = *(const float4*)(arow + (kk + 1) * 32);
      *(float4*)(&rn[4]) = *(const float4*)(arow + (kk + 1) * 32 + 4);
    }

    short8 ah, al;
#pragma unroll
    for (int j = 0; j < 8; ++j) {
      float f = ra[j];
      unsigned short h = f32_bf16_rne(f);
      float hf = __uint_as_float((unsigned int)h << 16);
      ah[j] = (short)h;
      al[j] = (short)f32_bf16_rne(f - hf);
    }
    __syncthreads();

#pragma unroll
    for (int nt = 0; nt < 8; ++nt) {
      short8 bh = *(const short8*)(BhS + ((size_t)nt * 64 + lane) * 8);
      short8 bl = *(const short8*)(BlS + ((size_t)nt * 64 + lane) * 8);
      acc[nt] = __builtin_amdgcn_mfma_f32_16x16x32_bf16(ah, bh, acc[nt], 0, 0, 0);
      acc[nt] = __builtin_amdgcn_mfma_f32_16x16x32_bf16(al, bh, acc[nt], 0, 0, 0);
      acc[nt] = __builtin_amdgcn_mfma_f32_16x16x32_bf16(ah, bl, acc[nt], 0, 0, 0);
    }
#pragma unroll
    for (int j = 0; j < 8; ++j) ra[j] = rn[j];
  }

#pragma unroll
  for (int nt = 0; nt < 8; ++nt) {
    float bv = bias[nt * 16 + col];
#pragma unroll
    for (int rr = 0; rr < 4; ++rr) {
      int row = m0 + quad * 4 + rr;
      if (row < N_NODES)
        H[(size_t)row * HID + nt * 16 + col] = acc[nt][rr] + bv;
    }
  }
}

// ---------------- merged scan over 120000 padded counters --------------------
static __device__ __forceinline__ int padded_cnt(const int* ecp, const int* ncp, int i) {
  return (i < N_EDGES) ? ecp[i * EPAD] : ncp[(i - N_EDGES) * NPAD];
}

__global__ __launch_bounds__(1024) void scan_block(const int* __restrict__ ecp,
                                                   const int* __restrict__ ncp,
                                                   int* __restrict__ ptr,
                                                   int* __restrict__ partials, int n)
{
  __shared__ int s[1024];
  int tid = threadIdx.x;
  int i = blockIdx.x * 1024 + tid;
  int v = (i < n) ? padded_cnt(ecp, ncp, i) : 0;
  s[tid] = v;
  __syncthreads();
  for (int off = 1; off < 1024; off <<= 1) {
    int add = (tid >= off) ? s[tid - off] : 0;
    __syncthreads();
    s[tid] += add;
    __syncthreads();
  }
  if (i < n) ptr[i] = s[tid] - v;            // exclusive
  if (tid == 1023) partials[blockIdx.x] = s[1023];
}

__global__ __launch_bounds__(1024) void scan_partials(int* __restrict__ partials, int nb,
                                                      int* __restrict__ ptr, int n)
{
  __shared__ int s[1024];
  int tid = threadIdx.x;
  int v = (tid < nb) ? partials[tid] : 0;
  s[tid] = v;
  __syncthreads();
  for (int off = 1; off < 1024; off <<= 1) {
    int add = (tid >= off) ? s[tid - off] : 0;
    __syncthreads();
    s[tid] += add;
    __syncthreads();
  }
  if (tid < nb) partials[tid] = s[tid] - v;  // exclusive block offsets
  if (tid == 0) ptr[n] = s[1023];            // grand total
}

// add partials AND preload padded cursors with final pointer values
__global__ void scan_add(int* __restrict__ ptr, const int* __restrict__ partials,
                         int* __restrict__ ecp, int* __restrict__ ncp, int n)
{
  int i = blockIdx.x * 1024 + threadIdx.x;
  if (i >= n) return;
  int v = ptr[i] + partials[blockIdx.x];
  ptr[i] = v;
  if (i < N_EDGES) ecp[i * EPAD] = v;
  else ncp[(i - N_EDGES) * NPAD] = v - NOFF;   // pre-biased into ncols space
}

// ---------- fused: edge fill + node fill + colsum(H) -------------------------
__global__ __launch_bounds__(256) void fill_colsum_kernel(
    const int* __restrict__ node_idx, const int* __restrict__ edge_idx,
    int* __restrict__ ecp, int* __restrict__ ncp,
    int* __restrict__ ecols, int* __restrict__ ncols,
    const float* __restrict__ H, float* __restrict__ gsum)
{
  __shared__ float red[4][HID];
  int bid = blockIdx.x;
  int tid = threadIdx.x;
  if (bid < FILLE_BLOCKS) {
    for (int i = bid * 256 + tid; i < N_INC; i += FILLE_BLOCKS * 256) {
      int ed = edge_idx[i];
      int nd = node_idx[i];
      int p = atomicAdd(&ecp[ed * EPAD], 1);
      ecols[p] = nd;
    }
    return;
  }
  bid -= FILLE_BLOCKS;
  if (bid < FILLN_BLOCKS) {
    for (int i = bid * 256 + tid; i < N_INC; i += FILLN_BLOCKS * 256) {
      int ed = edge_idx[i];
      int nd = node_idx[i];
      int q = atomicAdd(&ncp[nd * NPAD], 1);
      ncols[q] = ed;
    }
    return;
  }
  bid -= FILLN_BLOCKS;
  // colsum role
  int wave = tid >> 6, lane = tid & 63;
  float sx = 0.f, sy = 0.f;
  for (int r = bid * 4 + wave; r < N_NODES; r += CS_BLOCKS * 4) {
    float2 v = *(const float2*)(H + (size_t)r * HID + lane * 2);
    sx += v.x;
    sy += v.y;
  }
  red[wave][lane * 2] = sx;
  red[wave][lane * 2 + 1] = sy;
  __syncthreads();
  if (wave == 0) {
    float ax = red[0][lane * 2] + red[1][lane * 2] + red[2][lane * 2] + red[3][lane * 2];
    float ay = red[0][lane * 2 + 1] + red[1][lane * 2 + 1] + red[2][lane * 2 + 1] + red[3][lane * 2 + 1];
    atomicAdd(&gsum[lane * 2], ax);
    atomicAdd(&gsum[lane * 2 + 1], ay);
  }
}

// ---------------- standalone colsum (layer 2) --------------------------------
__global__ __launch_bounds__(256) void colsum_kernel(const float* __restrict__ H, float* __restrict__ gsum)
{
  __shared__ float red[4][HID];
  int wave = threadIdx.x >> 6, lane = threadIdx.x & 63;
  float sx = 0.f, sy = 0.f;
  for (int r = blockIdx.x * 4 + wave; r < N_NODES; r += gridDim.x * 4) {
    float2 v = *(const float2*)(H + (size_t)r * HID + lane * 2);
    sx += v.x;
    sy += v.y;
  }
  red[wave][lane * 2] = sx;
  red[wave][lane * 2 + 1] = sy;
  __syncthreads();
  if (wave == 0) {
    float ax = red[0][lane * 2] + red[1][lane * 2] + red[2][lane * 2] + red[3][lane * 2];
    float ay = red[0][lane * 2 + 1] + red[1][lane * 2 + 1] + red[2][lane * 2 + 1] + red[3][lane * 2 + 1];
    atomicAdd(&gsum[lane * 2], ax);
    atomicAdd(&gsum[lane * 2 + 1], ay);
  }
}

// ---------------- hypernet: scale = relu(g@W1+b1)@W2 + b2 ----------------
__global__ __launch_bounds__(128) void scale_kernel(const float* __restrict__ gsum,
    const float* __restrict__ W1, const float* __restrict__ b1,
    const float* __restrict__ W2, const float* __restrict__ b2,
    float* __restrict__ scale)
{
  __shared__ float g[HID], t[HID];
  int c = threadIdx.x;
  g[c] = gsum[c] * (1.0f / (float)N_NODES);
  __syncthreads();
  float acc = b1[c];
#pragma unroll 8
  for (int k = 0; k < HID; ++k) acc += g[k] * W1[(size_t)k * HID + c];
  t[c] = fmaxf(acc, 0.f);
  __syncthreads();
  float acc2 = b2[c];
#pragma unroll 8
  for (int k = 0; k < HID; ++k) acc2 += t[k] * W2[(size_t)k * HID + c];
  scale[c] = acc2;
}

// ---------------- edge aggregation: e_feat[e] = mean_{nodes in e} h[node] ----
__global__ __launch_bounds__(256) void edge_agg_kernel(
    const float* __restrict__ H, const int* __restrict__ eptr,
    const int* __restrict__ ecols, float* __restrict__ E)
{
  int gw = (blockIdx.x * blockDim.x + threadIdx.x) >> 6;
  int lane = threadIdx.x & 63;
  if (gw >= N_EDGES) return;
  int p0 = eptr[gw], p1 = eptr[gw + 1];
  float2 a0 = make_float2(0.f, 0.f), a1 = make_float2(0.f, 0.f);
  for (int base = p0; base < p1; base += 64) {
    int cnt = min(64, p1 - base);
    int idx = (base + lane < p1) ? ecols[base + lane] : 0;
    int j = 0;
    for (; j + 1 < cnt; j += 2) {
      int n0 = __shfl(idx, j, 64);
      int n1 = __shfl(idx, j + 1, 64);
      float2 v0 = *(const float2*)(H + (size_t)n0 * HID + lane * 2);
      float2 v1 = *(const float2*)(H + (size_t)n1 * HID + lane * 2);
      a0.x += v0.x; a0.y += v0.y;
      a1.x += v1.x; a1.y += v1.y;
    }
    if (j < cnt) {
      int n0 = __shfl(idx, j, 64);
      float2 v0 = *(const float2*)(H + (size_t)n0 * HID + lane * 2);
      a0.x += v0.x; a0.y += v0.y;
    }
  }
  float inv = 1.f / (float)max(p1 - p0, 1);
  float2 o = make_float2((a0.x + a1.x) * inv, (a0.y + a1.y) * inv);
  *(float2*)(E + (size_t)gw * HID + lane * 2) = o;
}

// ---------------- node aggregation + scale + relu (writes h in place) --------
__global__ __launch_bounds__(256) void node_agg_kernel(
    const float* __restrict__ E, const int* __restrict__ nptr,
    const int* __restrict__ ncols, const float* __restrict__ scale,
    float* __restrict__ H)
{
  int gw = (blockIdx.x * blockDim.x + threadIdx.x) >> 6;
  int lane = threadIdx.x & 63;
  if (gw >= N_NODES) return;
  int p0 = nptr[gw] - NOFF, p1 = nptr[gw + 1] - NOFF;
  float2 a0 = make_float2(0.f, 0.f), a1 = make_float2(0.f, 0.f);
  for (int base = p0; base < p1; base += 64) {
    int cnt = min(64, p1 - base);
    int idx = (base + lane < p1) ? ncols[base + lane] : 0;
    int j = 0;
    for (; j + 1 < cnt; j += 2) {
      int e0 = __shfl(idx, j, 64);
      int e1 = __shfl(idx, j + 1, 64);
      float2 v0 = *(const float2*)(E + (size_t)e0 * HID + lane * 2);
      float2 v1 = *(const float2*)(E + (size_t)e1 * HID + lane * 2);
      a0.x += v0.x; a0.y += v0.y;
      a1.x += v1.x; a1.y += v1.y;
    }
    if (j < cnt) {
      int e0 = __shfl(idx, j, 64);
      float2 v0 = *(const float2*)(E + (size_t)e0 * HID + lane * 2);
      a0.x += v0.x; a0.y += v0.y;
    }
  }
  float inv = 1.f / (float)max(p1 - p0, 1);
  float2 sc = *(const float2*)(scale + lane * 2);
  float2 o;
  o.x = fmaxf((a0.x + a1.x) * inv * sc.x, 0.f);
  o.y = fmaxf((a0.y + a1.y) * inv * sc.y, 0.f);
  *(float2*)(H + (size_t)gw * HID + lane * 2) = o;
}

// ---------------- launch ----------------
extern "C" void kernel_launch(void* const* d_in, const int* in_sizes, int n_in,
                              void* d_out, int out_size, void* d_ws, size_t ws_size,
                              hipStream_t stream)
{
  const float* text = (const float*)d_in[0];
  const float* Wp   = (const float*)d_in[1];
  const float* bp   = (const float*)d_in[2];
  const float* W1a  = (const float*)d_in[3];
  const float* b1a  = (const float*)d_in[4];
  const float* W2a  = (const float*)d_in[5];
  const float* b2a  = (const float*)d_in[6];
  const float* W1b  = (const float*)d_in[7];
  const float* b1b  = (const float*)d_in[8];
  const float* W2b  = (const float*)d_in[9];
  const float* b2b  = (const float*)d_in[10];
  const int* node_idx = (const int*)d_in[11];
  const int* edge_idx = (const int*)d_in[12];
  float* H = (float*)d_out;

  // ---- workspace layout (bytes) ----
  char* ws = (char*)d_ws;
  int*   ecp   = (int*)(ws + 0);                         // 20000*EPAD ints = 640,000 B
  int*   ncp   = (int*)(ws + 640000);                    // 100000*NPAD ints = 1,600,000 B
  float* gsum0 = (float*)(ws + 2240000);                 // 512 B
  float* gsum1 = (float*)(ws + 2240512);                 // 512 B
  const size_t zero_bytes = 2241024;
  int*   cptr  = (int*)(ws + 2241024);                   // 120001 ints (eptr||nptr+NOFF)
  int*   eptr  = cptr;
  int*   nptr  = cptr + N_EDGES;
  int*   ecols = (int*)(ws + 2721056);                   // 800000 ints
  int*   ncols = (int*)(ws + 5921056);                   // 800000 ints
  float* scale0 = (float*)(ws + 9121056);                // 128
  float* scale1 = (float*)(ws + 9121568);                // 128
  int*   partials = (int*)(ws + 9122080);                // 1024 ints
  float* efeat = (float*)(ws + 9126176);                 // 20000*128 floats -> ends ~19.4MB
  // Bh/Bl overlay ecols: live only from wprep until fill
  unsigned short* Bh = (unsigned short*)(ws + 2721056);  // 96 KB
  unsigned short* Bl = (unsigned short*)(ws + 2819360);  // 96 KB

  hipMemsetAsync(ws, 0, zero_bytes, stream);

  // W prep, then fused projection + counting
  wprep_kernel<<<96, 64, 0, stream>>>(Wp, Bh, Bl);
  proj_count_kernel<<<PROJ_BLOCKS + CNT_BLOCKS, 256, 0, stream>>>(
      text, Bh, Bl, bp, H, node_idx, edge_idx, ecp, ncp);

  // merged scan (120000) + cursor preload
  scan_block<<<118, 1024, 0, stream>>>(ecp, ncp, cptr, partials, 120000);
  scan_partials<<<1, 1024, 0, stream>>>(partials, 118, cptr, 120000);
  scan_add<<<118, 1024, 0, stream>>>(cptr, partials, ecp, ncp, 120000);

  // fused fills + colsum (layer 1)
  fill_colsum_kernel<<<FILLE_BLOCKS + FILLN_BLOCKS + CS_BLOCKS, 256, 0, stream>>>(
      node_idx, edge_idx, ecp, ncp, ecols, ncols, H, gsum0);

  // layer 1
  scale_kernel<<<1, 128, 0, stream>>>(gsum0, W1a, b1a, W2a, b2a, scale0);
  edge_agg_kernel<<<(N_EDGES * 64) / 256, 256, 0, stream>>>(H, eptr, ecols, efeat);
  node_agg_kernel<<<(N_NODES * 64) / 256, 256, 0, stream>>>(efeat, nptr, ncols, scale0, H);

  // layer 2
  colsum_kernel<<<256, 256, 0, stream>>>(H, gsum1);
  scale_kernel<<<1, 128, 0, stream>>>(gsum1, W1b, b1b, W2b, b2b, scale1);
  edge_agg_kernel<<<(N_EDGES * 64) / 256, 256, 0, stream>>>(H, eptr, ecols, efeat);
  node_agg_kernel<<<(N_NODES * 64) / 256, 256, 0, stream>>>(efeat, nptr, ncols, scale1, H);
}

// Round 5
// 643.193 us; speedup vs baseline: 1.2471x; 1.2471x over previous
//
#include <hip/hip_runtime.h>

#define N_NODES 100000
#define N_EDGES 20000
#define N_INC   800000
#define TDIM    384
#define HID     128
#define NOFF    800000   // node-ptr offset in merged scan
#define EPAD    8        // edge cursor stride (ints) = 32B
#define NPAD    4        // node cursor stride (ints) = 16B

#define PROJ_BLOCKS 1563
#define CNT_BLOCKS  512
#define FILLE_BLOCKS 1024
#define FILLN_BLOCKS 1024
#define EAGG_BLOCKS 5000
#define NAGG_BLOCKS 2500

typedef __attribute__((ext_vector_type(8))) short short8;
typedef __attribute__((ext_vector_type(4))) float floatx4;

static __device__ __forceinline__ unsigned short f32_bf16_rne(float f) {
  unsigned int u = __float_as_uint(f);
  unsigned int r = u + 0x7FFFu + ((u >> 16) & 1u);
  return (unsigned short)(r >> 16);
}

// ---------------- W prep: split W into hi/lo bf16 in B-fragment order ---------
__global__ __launch_bounds__(64) void wprep_kernel(
    const float* __restrict__ W, unsigned short* __restrict__ Bh,
    unsigned short* __restrict__ Bl)
{
  int b = blockIdx.x;              // 0..95 = kk*8 + nt
  int lane = threadIdx.x;
  int kk = b >> 3, nt = b & 7;
  int col = lane & 15, quad = lane >> 4;
  size_t o = ((size_t)b * 64 + lane) * 8;
#pragma unroll
  for (int j = 0; j < 8; ++j) {
    int k = kk * 32 + quad * 8 + j;
    float w = W[(size_t)k * HID + nt * 16 + col];
    unsigned short h = f32_bf16_rne(w);
    float hf = __uint_as_float((unsigned int)h << 16);
    Bh[o + j] = h;
    Bl[o + j] = f32_bf16_rne(w - hf);
  }
}

// ------ fused: projection (MFMA bf16x3, writes Hb bf16 + exact colsum) + count
__global__ __launch_bounds__(256) void proj_count_kernel(
    const float* __restrict__ A, const unsigned short* __restrict__ Bh,
    const unsigned short* __restrict__ Bl, const float* __restrict__ bias,
    unsigned short* __restrict__ Hb, float* __restrict__ gsum0,
    const int* __restrict__ node_idx, const int* __restrict__ edge_idx,
    int* __restrict__ ecp, int* __restrict__ ncp)
{
  __shared__ unsigned short BhS[512 * 8];   // 8 KB
  __shared__ unsigned short BlS[512 * 8];   // 8 KB
  __shared__ float red[4][HID];             // 2 KB (epilogue colsum)
  const int tid = threadIdx.x;

  if (blockIdx.x >= PROJ_BLOCKS) {
    // ---- count role: fire-and-forget atomics on padded counters ----
    int start = (blockIdx.x - PROJ_BLOCKS) * 256 + tid;
    for (int i = start; i < N_INC; i += CNT_BLOCKS * 256) {
      int ed = edge_idx[i];
      int nd = node_idx[i];
      atomicAdd(&ecp[ed * EPAD], 1);
      atomicAdd(&ncp[nd * NPAD], 1);
    }
    return;
  }

  // ---- proj role ----
  const int wave = tid >> 6;
  const int lane = tid & 63;
  const int col = lane & 15;
  const int quad = lane >> 4;
  const int m0 = blockIdx.x * 64 + wave * 16;

  floatx4 acc[8];
#pragma unroll
  for (int nt = 0; nt < 8; ++nt) acc[nt] = (floatx4){0.f, 0.f, 0.f, 0.f};

  int r = m0 + col;
  if (r >= N_NODES) r = N_NODES - 1;        // clamp loads; stores guarded
  const float* arow = A + (size_t)r * TDIM + quad * 8;

  float ra[8];
  *(float4*)(&ra[0]) = *(const float4*)(arow);
  *(float4*)(&ra[4]) = *(const float4*)(arow + 4);

  for (int kk = 0; kk < 12; ++kk) {
    short8 sh0 = *(const short8*)(Bh + ((size_t)kk * 512 + tid) * 8);
    short8 sh1 = *(const short8*)(Bh + ((size_t)kk * 512 + tid + 256) * 8);
    short8 sl0 = *(const short8*)(Bl + ((size_t)kk * 512 + tid) * 8);
    short8 sl1 = *(const short8*)(Bl + ((size_t)kk * 512 + tid + 256) * 8);
    __syncthreads();
    *(short8*)(BhS + (size_t)tid * 8) = sh0;
    *(short8*)(BhS + ((size_t)tid + 256) * 8) = sh1;
    *(short8*)(BlS + (size_t)tid * 8) = sl0;
    *(short8*)(BlS + ((size_t)tid + 256) * 8) = sl1;

    float rn[8];
    if (kk < 11) {
      *(float4*)(&rn[0]) = *(const float4*)(arow + (kk + 1) * 32);
      *(float4*)(&rn[4]) = *(const float4*)(arow + (kk + 1) * 32 + 4);
    }

    short8 ah, al;
#pragma unroll
    for (int j = 0; j < 8; ++j) {
      float f = ra[j];
      unsigned short h = f32_bf16_rne(f);
      float hf = __uint_as_float((unsigned int)h << 16);
      ah[j] = (short)h;
      al[j] = (short)f32_bf16_rne(f - hf);
    }
    __syncthreads();

#pragma unroll
    for (int nt = 0; nt < 8; ++nt) {
      short8 bh = *(const short8*)(BhS + ((size_t)nt * 64 + lane) * 8);
      short8 bl = *(const short8*)(BlS + ((size_t)nt * 64 + lane) * 8);
      acc[nt] = __builtin_amdgcn_mfma_f32_16x16x32_bf16(ah, bh, acc[nt], 0, 0, 0);
      acc[nt] = __builtin_amdgcn_mfma_f32_16x16x32_bf16(al, bh, acc[nt], 0, 0, 0);
      acc[nt] = __builtin_amdgcn_mfma_f32_16x16x32_bf16(ah, bl, acc[nt], 0, 0, 0);
    }
#pragma unroll
    for (int j = 0; j < 8; ++j) ra[j] = rn[j];
  }

  // epilogue: +bias, write Hb (bf16), exact fp32 column partials -> gsum0
#pragma unroll
  for (int nt = 0; nt < 8; ++nt) {
    float bv = bias[nt * 16 + col];
    float p = 0.f;
#pragma unroll
    for (int rr = 0; rr < 4; ++rr) {
      int row = m0 + quad * 4 + rr;
      float v = acc[nt][rr] + bv;
      if (row < N_NODES) {
        Hb[(size_t)row * HID + nt * 16 + col] = f32_bf16_rne(v);
        p += v;
      }
    }
    p += __shfl_xor(p, 16, 64);   // sum across quad bit 0 (rows)
    p += __shfl_xor(p, 32, 64);   // sum across quad bit 1 (rows)
    if (quad == 0) red[wave][nt * 16 + col] = p;
  }
  __syncthreads();
  if (tid < HID) {
    float a = red[0][tid] + red[1][tid] + red[2][tid] + red[3][tid];
    atomicAdd(&gsum0[(blockIdx.x & 7) * HID + tid], a);
  }
}

// ---------------- merged scan over 120000 padded counters --------------------
static __device__ __forceinline__ int padded_cnt(const int* ecp, const int* ncp, int i) {
  return (i < N_EDGES) ? ecp[i * EPAD] : ncp[(i - N_EDGES) * NPAD];
}

__global__ __launch_bounds__(1024) void scan_block(const int* __restrict__ ecp,
                                                   const int* __restrict__ ncp,
                                                   int* __restrict__ ptr,
                                                   int* __restrict__ partials, int n)
{
  __shared__ int s[1024];
  int tid = threadIdx.x;
  int i = blockIdx.x * 1024 + tid;
  int v = (i < n) ? padded_cnt(ecp, ncp, i) : 0;
  s[tid] = v;
  __syncthreads();
  for (int off = 1; off < 1024; off <<= 1) {
    int add = (tid >= off) ? s[tid - off] : 0;
    __syncthreads();
    s[tid] += add;
    __syncthreads();
  }
  if (i < n) ptr[i] = s[tid] - v;            // exclusive
  if (tid == 1023) partials[blockIdx.x] = s[1023];
}

__global__ __launch_bounds__(1024) void scan_partials(int* __restrict__ partials, int nb,
                                                      int* __restrict__ ptr, int n)
{
  __shared__ int s[1024];
  int tid = threadIdx.x;
  int v = (tid < nb) ? partials[tid] : 0;
  s[tid] = v;
  __syncthreads();
  for (int off = 1; off < 1024; off <<= 1) {
    int add = (tid >= off) ? s[tid - off] : 0;
    __syncthreads();
    s[tid] += add;
    __syncthreads();
  }
  if (tid < nb) partials[tid] = s[tid] - v;  // exclusive block offsets
  if (tid == 0) ptr[n] = s[1023];            // grand total
}

// add partials AND preload padded cursors with final pointer values
__global__ void scan_add(int* __restrict__ ptr, const int* __restrict__ partials,
                         int* __restrict__ ecp, int* __restrict__ ncp, int n)
{
  int i = blockIdx.x * 1024 + threadIdx.x;
  if (i >= n) return;
  int v = ptr[i] + partials[blockIdx.x];
  ptr[i] = v;
  if (i < N_EDGES) ecp[i * EPAD] = v;
  else ncp[(i - N_EDGES) * NPAD] = v - NOFF;   // pre-biased into ncols space
}

// ---------- fused: edge fill + node fill ------------------------------------
__global__ __launch_bounds__(256) void fill_kernel(
    const int* __restrict__ node_idx, const int* __restrict__ edge_idx,
    int* __restrict__ ecp, int* __restrict__ ncp,
    int* __restrict__ ecols, int* __restrict__ ncols)
{
  int bid = blockIdx.x;
  int tid = threadIdx.x;
  if (bid < FILLE_BLOCKS) {
    for (int i = bid * 256 + tid; i < N_INC; i += FILLE_BLOCKS * 256) {
      int ed = edge_idx[i];
      int nd = node_idx[i];
      int p = atomicAdd(&ecp[ed * EPAD], 1);
      ecols[p] = nd;
    }
  } else {
    bid -= FILLE_BLOCKS;
    for (int i = bid * 256 + tid; i < N_INC; i += FILLN_BLOCKS * 256) {
      int ed = edge_idx[i];
      int nd = node_idx[i];
      int q = atomicAdd(&ncp[nd * NPAD], 1);
      ncols[q] = ed;
    }
  }
}

// ---- fused: edge aggregation (bf16 gather, fp32 acc) + scale hypernet ------
__global__ __launch_bounds__(256) void edge_agg_scale_kernel(
    const unsigned short* __restrict__ Hb, const int* __restrict__ eptr,
    const int* __restrict__ ecols, unsigned short* __restrict__ Eb,
    const float* __restrict__ gsum,
    const float* __restrict__ W1, const float* __restrict__ b1,
    const float* __restrict__ W2, const float* __restrict__ b2,
    float* __restrict__ scale)
{
  if (blockIdx.x >= EAGG_BLOCKS) {
    // ---- scale role: scale = relu(g@W1+b1)@W2 + b2 (threads 0..127) ----
    __shared__ float g[HID], t[HID];
    int c = threadIdx.x;
    if (c < HID) {
      float s = 0.f;
#pragma unroll
      for (int k = 0; k < 8; ++k) s += gsum[k * HID + c];
      g[c] = s * (1.0f / (float)N_NODES);
    }
    __syncthreads();
    if (c < HID) {
      float acc = b1[c];
#pragma unroll 8
      for (int k = 0; k < HID; ++k) acc += g[k] * W1[(size_t)k * HID + c];
      t[c] = fmaxf(acc, 0.f);
    }
    __syncthreads();
    if (c < HID) {
      float acc2 = b2[c];
#pragma unroll 8
      for (int k = 0; k < HID; ++k) acc2 += t[k] * W2[(size_t)k * HID + c];
      scale[c] = acc2;
    }
    return;
  }
  int gw = blockIdx.x * 4 + (threadIdx.x >> 6);
  int lane = threadIdx.x & 63;
  int p0 = eptr[gw], p1 = eptr[gw + 1];
  float ax0 = 0.f, ay0 = 0.f, ax1 = 0.f, ay1 = 0.f;
  float ax2 = 0.f, ay2 = 0.f, ax3 = 0.f, ay3 = 0.f;
  for (int base = p0; base < p1; base += 64) {
    int cnt = min(64, p1 - base);
    int idx = (base + lane < p1) ? ecols[base + lane] : 0;
    int j = 0;
    for (; j + 3 < cnt; j += 4) {
      int n0 = __shfl(idx, j, 64);
      int n1 = __shfl(idx, j + 1, 64);
      int n2 = __shfl(idx, j + 2, 64);
      int n3 = __shfl(idx, j + 3, 64);
      unsigned v0 = *(const unsigned*)(Hb + (size_t)n0 * HID + lane * 2);
      unsigned v1 = *(const unsigned*)(Hb + (size_t)n1 * HID + lane * 2);
      unsigned v2 = *(const unsigned*)(Hb + (size_t)n2 * HID + lane * 2);
      unsigned v3 = *(const unsigned*)(Hb + (size_t)n3 * HID + lane * 2);
      ax0 += __uint_as_float(v0 << 16); ay0 += __uint_as_float(v0 & 0xffff0000u);
      ax1 += __uint_as_float(v1 << 16); ay1 += __uint_as_float(v1 & 0xffff0000u);
      ax2 += __uint_as_float(v2 << 16); ay2 += __uint_as_float(v2 & 0xffff0000u);
      ax3 += __uint_as_float(v3 << 16); ay3 += __uint_as_float(v3 & 0xffff0000u);
    }
    for (; j < cnt; ++j) {
      int n0 = __shfl(idx, j, 64);
      unsigned v0 = *(const unsigned*)(Hb + (size_t)n0 * HID + lane * 2);
      ax0 += __uint_as_float(v0 << 16); ay0 += __uint_as_float(v0 & 0xffff0000u);
    }
  }
  float inv = 1.f / (float)max(p1 - p0, 1);
  float sx = ((ax0 + ax1) + (ax2 + ax3)) * inv;
  float sy = ((ay0 + ay1) + (ay2 + ay3)) * inv;
  unsigned pk = ((unsigned)f32_bf16_rne(sy) << 16) | f32_bf16_rne(sx);
  *(unsigned*)(Eb + (size_t)gw * HID + lane * 2) = pk;
}

// --- node aggregation (bf16 gather) + scale + relu; aux: write Hb + colsum ---
__global__ __launch_bounds__(256) void node_agg_kernel(
    const unsigned short* __restrict__ Eb, const int* __restrict__ nptr,
    const int* __restrict__ ncols, const float* __restrict__ scale,
    unsigned short* __restrict__ Hb, float* __restrict__ H,
    float* __restrict__ gsum, int do_aux)
{
  __shared__ float red[4][HID];
  int wave = threadIdx.x >> 6, lane = threadIdx.x & 63;
  float2 sc = *(const float2*)(scale + lane * 2);
  float csx = 0.f, csy = 0.f;
  for (int gw = blockIdx.x * 4 + wave; gw < N_NODES; gw += NAGG_BLOCKS * 4) {
    int p0 = nptr[gw] - NOFF, p1 = nptr[gw + 1] - NOFF;
    float ax0 = 0.f, ay0 = 0.f, ax1 = 0.f, ay1 = 0.f;
    float ax2 = 0.f, ay2 = 0.f, ax3 = 0.f, ay3 = 0.f;
    for (int base = p0; base < p1; base += 64) {
      int cnt = min(64, p1 - base);
      int idx = (base + lane < p1) ? ncols[base + lane] : 0;
      int j = 0;
      for (; j + 3 < cnt; j += 4) {
        int e0 = __shfl(idx, j, 64);
        int e1 = __shfl(idx, j + 1, 64);
        int e2 = __shfl(idx, j + 2, 64);
        int e3 = __shfl(idx, j + 3, 64);
        unsigned v0 = *(const unsigned*)(Eb + (size_t)e0 * HID + lane * 2);
        unsigned v1 = *(const unsigned*)(Eb + (size_t)e1 * HID + lane * 2);
        unsigned v2 = *(const unsigned*)(Eb + (size_t)e2 * HID + lane * 2);
        unsigned v3 = *(const unsigned*)(Eb + (size_t)e3 * HID + lane * 2);
        ax0 += __uint_as_float(v0 << 16); ay0 += __uint_as_float(v0 & 0xffff0000u);
        ax1 += __uint_as_float(v1 << 16); ay1 += __uint_as_float(v1 & 0xffff0000u);
        ax2 += __uint_as_float(v2 << 16); ay2 += __uint_as_float(v2 & 0xffff0000u);
        ax3 += __uint_as_float(v3 << 16); ay3 += __uint_as_float(v3 & 0xffff0000u);
      }
      for (; j < cnt; ++j) {
        int e0 = __shfl(idx, j, 64);
        unsigned v0 = *(const unsigned*)(Eb + (size_t)e0 * HID + lane * 2);
        ax0 += __uint_as_float(v0 << 16); ay0 += __uint_as_float(v0 & 0xffff0000u);
      }
    }
    float inv = 1.f / (float)max(p1 - p0, 1);
    float ox = fmaxf(((ax0 + ax1) + (ax2 + ax3)) * inv * sc.x, 0.f);
    float oy = fmaxf(((ay0 + ay1) + (ay2 + ay3)) * inv * sc.y, 0.f);
    if (do_aux) {
      unsigned pk = ((unsigned)f32_bf16_rne(oy) << 16) | f32_bf16_rne(ox);
      *(unsigned*)(Hb + (size_t)gw * HID + lane * 2) = pk;
      csx += ox; csy += oy;
    } else {
      *(float2*)(H + (size_t)gw * HID + lane * 2) = make_float2(ox, oy);
    }
  }
  if (do_aux) {
    red[wave][lane * 2] = csx;
    red[wave][lane * 2 + 1] = csy;
    __syncthreads();
    if (threadIdx.x < HID) {
      int c = threadIdx.x;
      float a = red[0][c] + red[1][c] + red[2][c] + red[3][c];
      atomicAdd(&gsum[(blockIdx.x & 7) * HID + c], a);
    }
  }
}

// ---------------- launch ----------------
extern "C" void kernel_launch(void* const* d_in, const int* in_sizes, int n_in,
                              void* d_out, int out_size, void* d_ws, size_t ws_size,
                              hipStream_t stream)
{
  const float* text = (const float*)d_in[0];
  const float* Wp   = (const float*)d_in[1];
  const float* bp   = (const float*)d_in[2];
  const float* W1a  = (const float*)d_in[3];
  const float* b1a  = (const float*)d_in[4];
  const float* W2a  = (const float*)d_in[5];
  const float* b2a  = (const float*)d_in[6];
  const float* W1b  = (const float*)d_in[7];
  const float* b1b  = (const float*)d_in[8];
  const float* W2b  = (const float*)d_in[9];
  const float* b2b  = (const float*)d_in[10];
  const int* node_idx = (const int*)d_in[11];
  const int* edge_idx = (const int*)d_in[12];
  float* H = (float*)d_out;

  // ---- workspace layout (bytes) ----
  char* ws = (char*)d_ws;
  int*   ecp   = (int*)(ws + 0);                         // 20000*EPAD ints
  int*   ncp   = (int*)(ws + 640000);                    // 100000*NPAD ints
  float* gsum0 = (float*)(ws + 2240000);                 // 8*128 floats
  float* gsum1 = (float*)(ws + 2244096);                 // 8*128 floats
  const size_t zero_bytes = 2248192;
  int*   cptr  = (int*)(ws + 2248192);                   // 120001 ints (eptr||nptr)
  int*   eptr  = cptr;
  int*   nptr  = cptr + N_EDGES;
  int*   ecols = (int*)(ws + 2728208);                   // 800000 ints
  int*   ncols = (int*)(ws + 5928208);                   // 800000 ints
  float* scale0 = (float*)(ws + 9128208);                // 128
  float* scale1 = (float*)(ws + 9128720);                // 128
  int*   partials = (int*)(ws + 9129232);                // 1024 ints
  unsigned short* Eb = (unsigned short*)(ws + 9133328);  // 20000*128 bf16 (5.12 MB)
  unsigned short* Hb = (unsigned short*)(ws + 14253328); // 100000*128 bf16 (25.6 MB) -> ends ~39.9 MB
  // Bh/Bl overlay ecols: live only from wprep until fill
  unsigned short* Bh = (unsigned short*)(ws + 2728208);  // 96 KB
  unsigned short* Bl = (unsigned short*)(ws + 2826512);  // 96 KB

  hipMemsetAsync(ws, 0, zero_bytes, stream);

  // W prep, then fused projection(+colsum1, writes Hb) + counting
  wprep_kernel<<<96, 64, 0, stream>>>(Wp, Bh, Bl);
  proj_count_kernel<<<PROJ_BLOCKS + CNT_BLOCKS, 256, 0, stream>>>(
      text, Bh, Bl, bp, Hb, gsum0, node_idx, edge_idx, ecp, ncp);

  // merged scan (120000) + cursor preload
  scan_block<<<118, 1024, 0, stream>>>(ecp, ncp, cptr, partials, 120000);
  scan_partials<<<1, 1024, 0, stream>>>(partials, 118, cptr, 120000);
  scan_add<<<118, 1024, 0, stream>>>(cptr, partials, ecp, ncp, 120000);

  // fused fills
  fill_kernel<<<FILLE_BLOCKS + FILLN_BLOCKS, 256, 0, stream>>>(
      node_idx, edge_idx, ecp, ncp, ecols, ncols);

  // layer 1: edge agg (+scale1 role), node agg (writes Hb, fused colsum2)
  edge_agg_scale_kernel<<<EAGG_BLOCKS + 1, 256, 0, stream>>>(
      Hb, eptr, ecols, Eb, gsum0, W1a, b1a, W2a, b2a, scale0);
  node_agg_kernel<<<NAGG_BLOCKS, 256, 0, stream>>>(
      Eb, nptr, ncols, scale0, Hb, H, gsum1, 1);

  // layer 2: edge agg (+scale2 role), node agg (writes final fp32 H)
  edge_agg_scale_kernel<<<EAGG_BLOCKS + 1, 256, 0, stream>>>(
      Hb, eptr, ecols, Eb, gsum1, W1b, b1b, W2b, b2b, scale1);
  node_agg_kernel<<<NAGG_BLOCKS, 256, 0, stream>>>(
      Eb, nptr, ncols, scale1, Hb, H, gsum1, 0);
}